// Round 6
// baseline (87.120 us; speedup 1.0000x reference)
//
#include <hip/hip_runtime.h>
#include <hip/hip_bf16.h>

#define B_    64
#define DIM   640
#define TS    64
#define NT    10        // DIM/TS
#define NTP   55        // triu tile pairs
#define TRI   205120    // DIM*(DIM+1)/2
#define EPS   1e-5f
#define SQEPS 3.1622776601683794e-3f
#define KCH   16        // uint4 chunks per LDS tile row (256 B stride)

typedef __attribute__((ext_vector_type(8)))  short bf16x8;
typedef __attribute__((ext_vector_type(16))) float f32x16;

__device__ inline unsigned pk_bf16(float a, float b) {
    __hip_bfloat162 h = __float22bfloat162_rn(float2{a, b});
    return *reinterpret_cast<unsigned*>(&h);
}
__device__ inline float bfr(float x) {
    return __bfloat162float(__float2bfloat16(x));
}

// Thread role: c = t&15 (chunk col), rg = t>>4; rows rg+16*ff, ff=0..3.
// Loads the thread's 8 float4 of a 64x100 fp32 tile into registers.
__device__ inline void load_tile_regs(const float4* __restrict__ src, int t,
                                      float4 lo[4], float4 hi[4]) {
    const int c = t & 15, rg = t >> 4;
    #pragma unroll
    for (int ff = 0; ff < 4; ++ff) {
        const int r = rg + 16 * ff;
        lo[ff] = (c <= 12) ? src[(size_t)r * 25 + 2 * c]
                           : make_float4(0.f, 0.f, 0.f, 0.f);
        hi[ff] = (c < 12)  ? src[(size_t)r * 25 + 2 * c + 1]
                           : make_float4(0.f, 0.f, 0.f, 0.f);
    }
}

// Pack regs -> swizzled bf16 LDS tile (K zero-padded to 128) and write the
// per-row sum of squares of the bf16-rounded values into dRow[64].
__device__ inline void pack_tile(const float4 lo[4], const float4 hi[4],
                                 uint4* dst, float* dRow, int t) {
    const int c = t & 15, rg = t >> 4;
    #pragma unroll
    for (int ff = 0; ff < 4; ++ff) {
        const int r = rg + 16 * ff;
        uint4 p;
        p.x = pk_bf16(lo[ff].x, lo[ff].y);
        p.y = pk_bf16(lo[ff].z, lo[ff].w);
        p.z = pk_bf16(hi[ff].x, hi[ff].y);
        p.w = pk_bf16(hi[ff].z, hi[ff].w);
        dst[r * KCH + (c ^ (r & 15))] = p;
        float a0 = bfr(lo[ff].x), a1 = bfr(lo[ff].y);
        float a2 = bfr(lo[ff].z), a3 = bfr(lo[ff].w);
        float b0 = bfr(hi[ff].x), b1 = bfr(hi[ff].y);
        float b2 = bfr(hi[ff].z), b3 = bfr(hi[ff].w);
        float sq = a0*a0 + a1*a1 + a2*a2 + a3*a3
                 + b0*b0 + b1*b1 + b2*b2 + b3*b3;
        sq += __shfl_xor(sq, 1);
        sq += __shfl_xor(sq, 2);
        sq += __shfl_xor(sq, 4);
        sq += __shfl_xor(sq, 8);
        if (c == 0) dRow[r] = sq;
    }
}

// ---------------------------------------------------------------------------
// K1: one block per (b, strip s).  dcov row sums for rows [s*64, s*64+64),
// converting fp32 -> bf16 on the fly (no intermediate img).  No atomics.
// ---------------------------------------------------------------------------
__global__ __launch_bounds__(256, 3) void strip_kernel(
    const float* __restrict__ x, const float* __restrict__ temp,
    float* __restrict__ rowsum_g)
{
    __shared__ uint4 xown[TS * KCH];      // 16 KB
    __shared__ uint4 xj[TS * KCH];        // 16 KB
    __shared__ float dI[TS], dJ[TS];
    __shared__ float rpartw[2][TS];

    const int raw = blockIdx.x;                       // 640 % 8 == 0
    const int bid = (raw & 7) * (B_ * NT / 8) + (raw >> 3);
    const int b = bid / NT, s = bid % NT;
    const int t = threadIdx.x, wv = t >> 6, lane = t & 63;
    const int l31 = lane & 31, khalf = lane >> 5;
    const int iq = wv & 1, jq = wv >> 1;
    const float tts = expf(temp[0]);
    const float4* xb = (const float4*)x + (size_t)b * DIM * 25;

    float4 lo[4], hi[4], lo2[4], hi2[4];
    load_tile_regs(xb + (size_t)s * TS * 25, t, lo, hi);    // own strip
    load_tile_regs(xb, t, lo2, hi2);                        // j-tile 0
    pack_tile(lo, hi, xown, dI, t);
    pack_tile(lo2, hi2, xj, dJ, t);
    __syncthreads();

    // own-strip A fragments -> registers
    const int irow = iq * 32 + l31;
    bf16x8 bfrag[7];
    #pragma unroll
    for (int kk = 0; kk < 7; ++kk) {
        int c = kk * 2 + khalf;
        bfrag[kk] = *(const bf16x8*)&xown[irow * KCH + (c ^ (irow & 15))];
    }
    const float dIc = dI[irow];

    float rsum = 0.f;
    for (int jt = 0; jt < NT; ++jt) {
        if (jt + 1 < NT)
            load_tile_regs(xb + (size_t)(jt + 1) * TS * 25, t, lo2, hi2);
        f32x16 acc = {};
        const int jr = jq * 32 + l31;
        #pragma unroll
        for (int kk = 0; kk < 7; ++kk) {
            int c = kk * 2 + khalf;
            bf16x8 a = *(const bf16x8*)&xj[jr * KCH + (c ^ (jr & 15))];
            acc = __builtin_amdgcn_mfma_f32_32x32x16_bf16(a, bfrag[kk], acc, 0, 0, 0);
        }
        const bool dg = (jt == s);
        #pragma unroll
        for (int r = 0; r < 16; ++r) {
            int rf = (r & 3) + 8 * (r >> 2) + 4 * khalf;
            int jrow = jq * 32 + rf;
            float u = dJ[jrow] + dIc - 2.f * acc[r];
            rsum += (dg && jrow == irow)
                  ? SQEPS : sqrtf(tts * fmaxf(u, 0.f) + EPS);
        }
        __syncthreads();                       // done reading xj / dJ
        if (jt + 1 < NT) pack_tile(lo2, hi2, xj, dJ, t);
        __syncthreads();                       // next tile ready
    }

    rsum += __shfl_xor(rsum, 32);
    if (lane < 32) rpartw[jq][iq * 32 + lane] = rsum;
    __syncthreads();
    if (t < TS)
        rowsum_g[b * DIM + s * TS + t] = rpartw[0][t] + rpartw[1][t];
}

// XCD-grouped block id -> (b, ti, tj).  3520 % 8 == 0 -> bijective.
__device__ inline void decode_blk(int raw, int& b, int& ti, int& tj) {
    int bid = (raw & 7) * (B_ * NTP / 8) + (raw >> 3);
    b = bid / NTP;
    int tp = bid % NTP;
    int i = 0;
    while (tp >= NT - i) { tp -= NT - i; ++i; }
    ti = i; tj = i + tp;
}

// ---------------------------------------------------------------------------
// K2: one block per (b, triu tile pair).  Recompute tile from fp32 x (on-the-
// fly bf16 pack), center with rm/tm derived in-block from rowsum, write triu.
// ---------------------------------------------------------------------------
__global__ __launch_bounds__(256, 3) void write_kernel(
    const float* __restrict__ x, const float* __restrict__ temp,
    const float* __restrict__ rowsum_g, float* __restrict__ out)
{
    __shared__ uint4 xi[TS * KCH], xjb[TS * KCH];   // 32 KB
    __shared__ float dI[TS], dJ[TS], rmI[TS], rmJ[TS];
    __shared__ float red4[4];

    int b, ti, tj; decode_blk(blockIdx.x, b, ti, tj);
    const int t = threadIdx.x, wv = t >> 6, lane = t & 63;
    const int l31 = lane & 31, khalf = lane >> 5;
    const int i0 = ti * TS, j0 = tj * TS;
    const float tts = expf(temp[0]);
    const float4* xb = (const float4*)x + (size_t)b * DIM * 25;

    float4 lo[4], hi[4], lo2[4], hi2[4];
    load_tile_regs(xb + (size_t)i0 * 25, t, lo, hi);
    if (ti != tj) load_tile_regs(xb + (size_t)j0 * 25, t, lo2, hi2);

    // deterministic per-batch total mean (all loads L2-resident)
    float ps = 0.f;
    for (int k = t; k < DIM; k += 256) ps += rowsum_g[b * DIM + k];
    ps += __shfl_xor(ps, 1);  ps += __shfl_xor(ps, 2);
    ps += __shfl_xor(ps, 4);  ps += __shfl_xor(ps, 8);
    ps += __shfl_xor(ps, 16); ps += __shfl_xor(ps, 32);
    if (lane == 0) red4[wv] = ps;

    pack_tile(lo, hi, xi, dI, t);
    if (ti != tj) pack_tile(lo2, hi2, xjb, dJ, t);

    const float invD = 1.0f / (float)DIM;
    if (t < TS)            rmI[t] = rowsum_g[b * DIM + i0 + t] * invD;
    else if (t < 2 * TS)   rmJ[t - TS] = rowsum_g[b * DIM + j0 + (t - TS)] * invD;
    __syncthreads();

    const float tm = (red4[0] + red4[1] + red4[2] + red4[3])
                   * (1.0f / ((float)DIM * (float)DIM));
    const uint4* xjp = (ti == tj) ? xi : xjb;
    const float* dJp = (ti == tj) ? dI : dJ;
    const float* rmJp = (ti == tj) ? rmI : rmJ;

    const int wm = wv >> 1, wn = wv & 1;
    const int arow = wm * 32 + l31, brow = wn * 32 + l31;
    f32x16 acc = {};
    #pragma unroll
    for (int kk = 0; kk < 7; ++kk) {
        int c = kk * 2 + khalf;
        bf16x8 a  = *(const bf16x8*)&xi[arow * KCH + (c ^ (arow & 15))];
        bf16x8 bb = *(const bf16x8*)&xjp[brow * KCH + (c ^ (brow & 15))];
        acc = __builtin_amdgcn_mfma_f32_32x32x16_bf16(a, bb, acc, 0, 0, 0);
    }

    const int col_l = wn * 32 + l31;
    const int gj = j0 + col_l;
    const float dJc = dJp[col_l], rmJc = rmJp[col_l];
    #pragma unroll
    for (int r = 0; r < 16; ++r) {
        int rf = (r & 3) + 8 * (r >> 2) + 4 * khalf;
        int row_l = wm * 32 + rf;
        int gi = i0 + row_l;
        float u = dI[row_l] + dJc - 2.f * acc[r];
        float v = (gi == gj) ? SQEPS : sqrtf(tts * fmaxf(u, 0.f) + EPS);
        float cv = v - rmI[row_l] - rmJc + tm;
        if (gj >= gi) {
            size_t idx = (size_t)b * TRI + (size_t)gi * DIM
                       - ((size_t)gi * (gi - 1)) / 2 - gi + gj;
            out[idx] = cv;
        }
    }
}

extern "C" void kernel_launch(void* const* d_in, const int* in_sizes, int n_in,
                              void* d_out, int out_size, void* d_ws, size_t ws_size,
                              hipStream_t stream)
{
    const float* x    = (const float*)d_in[0];
    const float* temp = (const float*)d_in[1];
    float* out      = (float*)d_out;
    float* rowsum_g = (float*)d_ws;             // [B_*DIM], fully overwritten

    strip_kernel<<<B_ * NT,  256, 0, stream>>>(x, temp, rowsum_g);
    write_kernel<<<B_ * NTP, 256, 0, stream>>>(x, temp, rowsum_g, out);
}

// Round 7
// 75.410 us; speedup vs baseline: 1.1553x; 1.1553x over previous
//
#include <hip/hip_runtime.h>
#include <hip/hip_bf16.h>

#define B_    64
#define DIM   640
#define TS    64
#define NT    10        // DIM/TS
#define NTP   55        // triu tile pairs
#define TRI   205120    // DIM*(DIM+1)/2
#define EPS   1e-5f
#define SQEPS 3.1622776601683794e-3f

typedef __attribute__((ext_vector_type(8)))  short bf16x8;
typedef __attribute__((ext_vector_type(16))) float f32x16;

__device__ inline unsigned pk_bf16(float a, float b) {
    __hip_bfloat162 h = __float22bfloat162_rn(float2{a, b});
    return *reinterpret_cast<unsigned*>(&h);
}

// Load this lane's 7 MFMA fragments (8 bf16 each) of one row directly from
// fp32 x. khalf picks chunk parity (chunk c = 8 floats [8c, 8c+8)).
// Returns fp32 sum of squares of the lane's half-row (chunks of its parity).
__device__ inline float ldfrag(const float4* __restrict__ rowp, int khalf,
                               bf16x8 fr[7]) {
    float sq = 0.f;
    union { bf16x8 v; unsigned u[4]; } p;
    float4 st[8];
    #pragma unroll
    for (int kk = 0; kk < 4; ++kk) {       // c = 2kk+khalf <= 7: no guards
        const int c = kk * 2 + khalf;
        st[2 * kk]     = rowp[2 * c];
        st[2 * kk + 1] = rowp[2 * c + 1];
    }
    #pragma unroll
    for (int kk = 0; kk < 4; ++kk) {
        float4 a = st[2 * kk], b = st[2 * kk + 1];
        sq += a.x*a.x + a.y*a.y + a.z*a.z + a.w*a.w
            + b.x*b.x + b.y*b.y + b.z*b.z + b.w*b.w;
        p.u[0] = pk_bf16(a.x, a.y); p.u[1] = pk_bf16(a.z, a.w);
        p.u[2] = pk_bf16(b.x, b.y); p.u[3] = pk_bf16(b.z, b.w);
        fr[kk] = p.v;
    }
    #pragma unroll
    for (int kk = 4; kk < 7; ++kk) {       // c in {8..13}: guard tail
        const int c = kk * 2 + khalf;
        float4 a = (c <= 12) ? rowp[2 * c]     : make_float4(0.f,0.f,0.f,0.f);
        float4 b = (c <  12) ? rowp[2 * c + 1] : make_float4(0.f,0.f,0.f,0.f);
        sq += a.x*a.x + a.y*a.y + a.z*a.z + a.w*a.w
            + b.x*b.x + b.y*b.y + b.z*b.z + b.w*b.w;
        p.u[0] = pk_bf16(a.x, a.y); p.u[1] = pk_bf16(a.z, a.w);
        p.u[2] = pk_bf16(b.x, b.y); p.u[3] = pk_bf16(b.z, b.w);
        fr[kk] = p.v;
    }
    return sq;
}

// ---------------------------------------------------------------------------
// K1: one block per (b, strip s, j-parity h).  dcov partial row sums for rows
// [s*64, s*64+64) over j-tiles of parity h.  All operands in registers; no
// LDS tiles, no syncs in the loop, no atomics.
// ---------------------------------------------------------------------------
__global__ __launch_bounds__(256, 4) void strip_kernel(
    const float* __restrict__ x, const float* __restrict__ temp,
    float* __restrict__ rowsum_part)
{
    __shared__ float rpartw[2][TS];

    const int raw = blockIdx.x;                       // 1280 % 8 == 0
    const int bid = (raw & 7) * 160 + (raw >> 3);     // XCD-grouped
    const int b = bid / 20, rem = bid % 20;
    const int s = rem >> 1, h = rem & 1;
    const int t = threadIdx.x, wv = t >> 6, lane = t & 63;
    const int l31 = lane & 31, khalf = lane >> 5;
    const int iq = wv & 1, jq = wv >> 1;
    const float tts = expf(temp[0]);
    const float* xb = x + (size_t)b * DIM * 100;

    const int irow = iq * 32 + l31;
    bf16x8 ifr[7];
    float sqi = ldfrag((const float4*)(xb + (size_t)(s * TS + irow) * 100),
                       khalf, ifr);
    const float dic = sqi + __shfl_xor(sqi, 32);

    float rsum = 0.f;
    for (int jj = 0; jj < 5; ++jj) {
        const int jt = h + 2 * jj;
        const int jr = jq * 32 + l31;
        bf16x8 jfr[7];
        float sqj = ldfrag((const float4*)(xb + (size_t)(jt * TS + jr) * 100),
                           khalf, jfr);
        float djf = sqj + __shfl_xor(sqj, 32);

        f32x16 acc = {};
        #pragma unroll
        for (int kk = 0; kk < 7; ++kk)
            acc = __builtin_amdgcn_mfma_f32_32x32x16_bf16(jfr[kk], ifr[kk],
                                                          acc, 0, 0, 0);
        const bool dg = (jt == s);
        #pragma unroll
        for (int r = 0; r < 16; ++r) {
            const int rf = (r & 3) + 8 * (r >> 2) + 4 * khalf;
            const int jrow = jq * 32 + rf;
            const float dj = __shfl(djf, rf);     // lane rf holds row jq*32+rf
            float u = dj + dic - 2.f * acc[r];
            rsum += (dg && jrow == irow)
                  ? SQEPS : sqrtf(tts * fmaxf(u, 0.f) + EPS);
        }
    }

    rsum += __shfl_xor(rsum, 32);
    if (lane < 32) rpartw[jq][iq * 32 + lane] = rsum;
    __syncthreads();
    if (t < TS)
        rowsum_part[h * (B_ * DIM) + b * DIM + s * TS + t]
            = rpartw[0][t] + rpartw[1][t];
}

// XCD-grouped block id -> (b, ti, tj).  3520 % 8 == 0 -> bijective.
__device__ inline void decode_blk(int raw, int& b, int& ti, int& tj) {
    int bid = (raw & 7) * (B_ * NTP / 8) + (raw >> 3);
    b = bid / NTP;
    int tp = bid % NTP;
    int i = 0;
    while (tp >= NT - i) { tp -= NT - i; ++i; }
    ti = i; tj = i + tp;
}

// ---------------------------------------------------------------------------
// K2: one block per (b, triu tile pair).  Register fragments from fp32 x,
// centering params from rowsum_part, packed-triu write.  One __syncthreads.
// ---------------------------------------------------------------------------
__global__ __launch_bounds__(256, 4) void write_kernel(
    const float* __restrict__ x, const float* __restrict__ temp,
    const float* __restrict__ rowsum_part, float* __restrict__ out)
{
    __shared__ float red4[4];

    int b, ti, tj; decode_blk(blockIdx.x, b, ti, tj);
    const int t = threadIdx.x, wv = t >> 6, lane = t & 63;
    const int l31 = lane & 31, khalf = lane >> 5;
    const int wm = wv >> 1, wn = wv & 1;
    const int i0 = ti * TS, j0 = tj * TS;
    const float tts = expf(temp[0]);
    const float invD = 1.0f / (float)DIM;
    const float* xb = x + (size_t)b * DIM * 100;
    const float* r0 = rowsum_part + b * DIM;
    const float* r1 = rowsum_part + B_ * DIM + b * DIM;

    // per-batch total mean (deterministic in-block reduce, L2-resident loads)
    float ps = 0.f;
    for (int k = t; k < DIM; k += 256) ps += r0[k] + r1[k];
    ps += __shfl_xor(ps, 1);  ps += __shfl_xor(ps, 2);
    ps += __shfl_xor(ps, 4);  ps += __shfl_xor(ps, 8);
    ps += __shfl_xor(ps, 16); ps += __shfl_xor(ps, 32);
    if (lane == 0) red4[wv] = ps;

    const int arow = wm * 32 + l31, brow = wn * 32 + l31;
    bf16x8 afr[7], bfr[7];
    float sqa = ldfrag((const float4*)(xb + (size_t)(i0 + arow) * 100),
                       khalf, afr);
    float sqb = ldfrag((const float4*)(xb + (size_t)(j0 + brow) * 100),
                       khalf, bfr);
    const float dif  = sqa + __shfl_xor(sqa, 32);
    const float djc  = sqb + __shfl_xor(sqb, 32);
    const float rmif = (r0[i0 + arow] + r1[i0 + arow]) * invD;
    const float rmjc = (r0[j0 + brow] + r1[j0 + brow]) * invD;

    f32x16 acc = {};
    #pragma unroll
    for (int kk = 0; kk < 7; ++kk)
        acc = __builtin_amdgcn_mfma_f32_32x32x16_bf16(afr[kk], bfr[kk],
                                                      acc, 0, 0, 0);
    __syncthreads();
    const float tm = (red4[0] + red4[1] + red4[2] + red4[3])
                   * (1.0f / ((float)DIM * (float)DIM));

    const int gj = j0 + wn * 32 + l31;
    #pragma unroll
    for (int r = 0; r < 16; ++r) {
        const int rf = (r & 3) + 8 * (r >> 2) + 4 * khalf;
        const int gi = i0 + wm * 32 + rf;
        const float di  = __shfl(dif, rf);
        const float rmi = __shfl(rmif, rf);
        float u = di + djc - 2.f * acc[r];
        float v = (gi == gj) ? SQEPS : sqrtf(tts * fmaxf(u, 0.f) + EPS);
        float cv = v - rmi - rmjc + tm;
        if (gj >= gi) {
            size_t idx = (size_t)b * TRI + (size_t)gi * DIM
                       - ((size_t)gi * (gi - 1)) / 2 - gi + gj;
            out[idx] = cv;
        }
    }
}

extern "C" void kernel_launch(void* const* d_in, const int* in_sizes, int n_in,
                              void* d_out, int out_size, void* d_ws, size_t ws_size,
                              hipStream_t stream)
{
    const float* x    = (const float*)d_in[0];
    const float* temp = (const float*)d_in[1];
    float* out         = (float*)d_out;
    float* rowsum_part = (float*)d_ws;     // [2][B_*DIM], fully overwritten

    strip_kernel<<<2 * B_ * NT, 256, 0, stream>>>(x, temp, rowsum_part);
    write_kernel<<<B_ * NTP,    256, 0, stream>>>(x, temp, rowsum_part, out);
}

// Round 8
// 67.196 us; speedup vs baseline: 1.2965x; 1.1222x over previous
//
#include <hip/hip_runtime.h>
#include <hip/hip_bf16.h>

#define B_    64
#define DIM   640
#define TS    64
#define NT    10        // DIM/TS
#define TRI   205120    // DIM*(DIM+1)/2
#define EPS   1e-5f
#define SQEPS 3.1622776601683794e-3f

typedef __attribute__((ext_vector_type(8)))  short bf16x8;
typedef __attribute__((ext_vector_type(16))) float f32x16;

__device__ inline unsigned pk_bf16(float a, float b) {
    __hip_bfloat162 h = __float22bfloat162_rn(float2{a, b});
    return *reinterpret_cast<unsigned*>(&h);
}
__device__ inline float fsq(float x) { return __builtin_amdgcn_sqrtf(x); }

// Load this lane's 7 MFMA fragments (8 bf16 each) of one row directly from
// fp32 x. khalf picks chunk parity (chunk c = 8 floats [8c, 8c+8)).
// Returns fp32 sum of squares of the lane's half-row.
__device__ inline float ldfrag(const float4* __restrict__ rowp, int khalf,
                               bf16x8 fr[7]) {
    float sq = 0.f;
    union { bf16x8 v; unsigned u[4]; } p;
    float4 st[8];
    #pragma unroll
    for (int kk = 0; kk < 4; ++kk) {       // c = 2kk+khalf <= 7: no guards
        const int c = kk * 2 + khalf;
        st[2 * kk]     = rowp[2 * c];
        st[2 * kk + 1] = rowp[2 * c + 1];
    }
    #pragma unroll
    for (int kk = 0; kk < 4; ++kk) {
        float4 a = st[2 * kk], b = st[2 * kk + 1];
        sq += a.x*a.x + a.y*a.y + a.z*a.z + a.w*a.w
            + b.x*b.x + b.y*b.y + b.z*b.z + b.w*b.w;
        p.u[0] = pk_bf16(a.x, a.y); p.u[1] = pk_bf16(a.z, a.w);
        p.u[2] = pk_bf16(b.x, b.y); p.u[3] = pk_bf16(b.z, b.w);
        fr[kk] = p.v;
    }
    #pragma unroll
    for (int kk = 4; kk < 7; ++kk) {       // c in {8..13}: guard tail
        const int c = kk * 2 + khalf;
        float4 a = (c <= 12) ? rowp[2 * c]     : make_float4(0.f,0.f,0.f,0.f);
        float4 b = (c <  12) ? rowp[2 * c + 1] : make_float4(0.f,0.f,0.f,0.f);
        sq += a.x*a.x + a.y*a.y + a.z*a.z + a.w*a.w
            + b.x*b.x + b.y*b.y + b.z*b.z + b.w*b.w;
        p.u[0] = pk_bf16(a.x, a.y); p.u[1] = pk_bf16(a.z, a.w);
        p.u[2] = pk_bf16(b.x, b.y); p.u[3] = pk_bf16(b.z, b.w);
        fr[kk] = p.v;
    }
    return sq;
}

// ---------------------------------------------------------------------------
// K1: one block per (b, strip s, j-parity h).  dcov partial row sums for rows
// [s*64, s*64+64) over j-tiles of parity h.  All register-resident.
// ---------------------------------------------------------------------------
__global__ __launch_bounds__(256, 4) void strip_kernel(
    const float* __restrict__ x, const float* __restrict__ temp,
    float* __restrict__ rowsum_part)
{
    __shared__ float rpartw[2][TS];

    const int raw = blockIdx.x;                       // 1280 % 8 == 0
    const int bid = (raw & 7) * 160 + (raw >> 3);     // XCD-grouped
    const int b = bid / 20, rem = bid % 20;
    const int s = rem >> 1, h = rem & 1;
    const int t = threadIdx.x, wv = t >> 6, lane = t & 63;
    const int l31 = lane & 31, khalf = lane >> 5;
    const int iq = wv & 1, jq = wv >> 1;
    const float tts = expf(temp[0]);
    const float* xb = x + (size_t)b * DIM * 100;

    const int irow = iq * 32 + l31;
    bf16x8 ifr[7];
    float sqi = ldfrag((const float4*)(xb + (size_t)(s * TS + irow) * 100),
                       khalf, ifr);
    const float dic = sqi + __shfl_xor(sqi, 32);

    float rsum = 0.f;
    for (int jj = 0; jj < 5; ++jj) {
        const int jt = h + 2 * jj;
        const int jr = jq * 32 + l31;
        bf16x8 jfr[7];
        float sqj = ldfrag((const float4*)(xb + (size_t)(jt * TS + jr) * 100),
                           khalf, jfr);
        float djf = sqj + __shfl_xor(sqj, 32);

        f32x16 acc = {};
        #pragma unroll
        for (int kk = 0; kk < 7; ++kk)
            acc = __builtin_amdgcn_mfma_f32_32x32x16_bf16(jfr[kk], ifr[kk],
                                                          acc, 0, 0, 0);
        const bool dg = (jt == s);
        #pragma unroll
        for (int r = 0; r < 16; ++r) {
            const int rf = (r & 3) + 8 * (r >> 2) + 4 * khalf;
            const int jrow = jq * 32 + rf;
            const float dj = __shfl(djf, rf);
            float u = dj + dic - 2.f * acc[r];
            rsum += (dg && jrow == irow)
                  ? SQEPS : fsq(tts * fmaxf(u, 0.f) + EPS);
        }
    }

    rsum += __shfl_xor(rsum, 32);
    if (lane < 32) rpartw[jq][iq * 32 + lane] = rsum;
    __syncthreads();
    if (t < TS)
        rowsum_part[h * (B_ * DIM) + b * DIM + s * TS + t]
            = rpartw[0][t] + rpartw[1][t];
}

// ---------------------------------------------------------------------------
// K2: one block per (b, strip-pair p, j-parity h).  Owns tiles
// {(p, j): j>=p, j&1==h} U {(9-p, j): j>=9-p, j&1==h}  ->  5 or 6 tiles.
// A-fragments + centering vector e[] amortized across the tiles.
// ---------------------------------------------------------------------------
__global__ __launch_bounds__(256, 3) void write_kernel(
    const float* __restrict__ x, const float* __restrict__ temp,
    const float* __restrict__ rowsum_part, float* __restrict__ out)
{
    __shared__ float e[DIM];
    __shared__ float red4[4];

    const int raw = blockIdx.x;                       // 640 % 8 == 0
    const int bid = (raw & 7) * 80 + (raw >> 3);      // XCD-grouped
    const int b = bid / 10, rem = bid % 10;
    const int p = rem >> 1, h = rem & 1;
    const int t = threadIdx.x, wv = t >> 6, lane = t & 63;
    const int l31 = lane & 31, khalf = lane >> 5;
    const int wm = wv >> 1, wn = wv & 1;
    const float tts = expf(temp[0]);
    const float* xb = x + (size_t)b * DIM * 100;
    const float* r0 = rowsum_part + b * DIM;
    const float* r1 = rowsum_part + (B_ * DIM) + b * DIM;

    // e[k] = tm/2 - rowmean[k]  =>  centered = v + e[gi] + e[gj]
    float ps = 0.f;
    for (int k = t; k < DIM; k += 256) {
        float rs = r0[k] + r1[k];
        e[k] = rs;
        ps += rs;
    }
    ps += __shfl_xor(ps, 1);  ps += __shfl_xor(ps, 2);
    ps += __shfl_xor(ps, 4);  ps += __shfl_xor(ps, 8);
    ps += __shfl_xor(ps, 16); ps += __shfl_xor(ps, 32);
    if (lane == 0) red4[wv] = ps;
    __syncthreads();
    const float tm = (red4[0] + red4[1] + red4[2] + red4[3])
                   * (1.0f / ((float)DIM * (float)DIM));
    const float invD = 1.0f / (float)DIM;
    for (int k = t; k < DIM; k += 256)
        e[k] = 0.5f * tm - e[k] * invD;
    __syncthreads();

    #pragma unroll
    for (int si = 0; si < 2; ++si) {
        const int s = si ? (9 - p) : p;
        const int jf = s + ((s ^ h) & 1);            // first j>=s, j&1==h
        if (jf >= NT) continue;
        const int i0 = s * TS;
        const int arow = wm * 32 + l31;

        bf16x8 afr[7];
        float sqa = ldfrag((const float4*)(xb + (size_t)(i0 + arow) * 100),
                           khalf, afr);
        const float dif = sqa + __shfl_xor(sqa, 32);

        for (int j = jf; j < NT; j += 2) {
            const int j0 = j * TS;
            const int brow = wn * 32 + l31;
            bf16x8 bfr7[7];
            float sqb = ldfrag((const float4*)(xb + (size_t)(j0 + brow) * 100),
                               khalf, bfr7);
            const float djc = sqb + __shfl_xor(sqb, 32);
            const int gj = j0 + brow;
            const float ejc = e[gj];

            f32x16 acc = {};
            #pragma unroll
            for (int kk = 0; kk < 7; ++kk)
                acc = __builtin_amdgcn_mfma_f32_32x32x16_bf16(afr[kk], bfr7[kk],
                                                              acc, 0, 0, 0);
            const bool dg = (j == s);
            #pragma unroll
            for (int g = 0; g < 4; ++g) {
                const int rbase = wm * 32 + 8 * g + 4 * khalf;  // local i row
                const float4 e4 = *(const float4*)&e[i0 + rbase];
                #pragma unroll
                for (int q = 0; q < 4; ++q) {
                    const int r  = 4 * g + q;
                    const int rf = 8 * g + 4 * khalf + q;
                    const int gi = i0 + rbase + q;
                    const float di = __shfl(dif, rf);
                    float u = di + djc - 2.f * acc[r];
                    float v = (dg && gi == gj)
                            ? SQEPS : fsq(tts * fmaxf(u, 0.f) + EPS);
                    float cv = v + ((const float*)&e4)[q] + ejc;
                    unsigned idx = (unsigned)b * TRI + (unsigned)gi * DIM
                                 - (((unsigned)gi * (unsigned)(gi - 1)) >> 1)
                                 - (unsigned)gi + (unsigned)gj;
                    if (!dg || gj >= gi) out[idx] = cv;
                }
            }
        }
    }
}

extern "C" void kernel_launch(void* const* d_in, const int* in_sizes, int n_in,
                              void* d_out, int out_size, void* d_ws, size_t ws_size,
                              hipStream_t stream)
{
    const float* x    = (const float*)d_in[0];
    const float* temp = (const float*)d_in[1];
    float* out         = (float*)d_out;
    float* rowsum_part = (float*)d_ws;     // [2][B_*DIM], fully overwritten

    strip_kernel<<<2 * B_ * NT, 256, 0, stream>>>(x, temp, rowsum_part);
    write_kernel<<<B_ * NT,     256, 0, stream>>>(x, temp, rowsum_part, out);
}

// Round 9
// 51.312 us; speedup vs baseline: 1.6979x; 1.3096x over previous
//
#include <hip/hip_runtime.h>
#include <hip/hip_bf16.h>

#define B_    64
#define DIM   640
#define TS    64
#define NT    10        // DIM/TS
#define TRI   205120    // DIM*(DIM+1)/2
#define EPS   1e-5f
#define SQEPS 3.1622776601683794e-3f
#define KCH   16        // uint4 chunks per img row (256 B row stride)
#define TILE_U4 1024    // uint4 per 64-row tile image (16 KB)
#define TILE_B  16384

typedef __attribute__((ext_vector_type(8)))  short bf16x8;
typedef __attribute__((ext_vector_type(16))) float f32x16;

__device__ inline unsigned pk_bf16(float a, float b) {
    __hip_bfloat162 h = __float22bfloat162_rn(float2{a, b});
    return *reinterpret_cast<unsigned*>(&h);
}
__device__ inline float bfr(float x) {
    return __bfloat162float(__float2bfloat16(x));
}
__device__ inline float fsq(float x) { return __builtin_amdgcn_sqrtf(x); }

__device__ inline void gload_lds16(const void* g, void* l) {
    __builtin_amdgcn_global_load_lds(
        (const __attribute__((address_space(1))) unsigned*)g,
        (__attribute__((address_space(3))) unsigned*)l, 16, 0, 0);
}
// stage one 16 KB tile: 4 waves x 4 segs x 64 lanes x 16 B (coalesced)
__device__ inline void stage_tile16(const char* __restrict__ gt, char* lt,
                                    int wv, int lane) {
    #pragma unroll
    for (int it = 0; it < 4; ++it) {
        const int seg = (wv * 4 + it) * 1024;
        gload_lds16(gt + seg + lane * 16, lt + seg);
    }
}

// ---------------------------------------------------------------------------
// K0 prep: per (b,s) convert 64x100 fp32 strip -> swizzled bf16 img tile
// (K zero-padded) + per-row sum of squares of bf16-rounded values.
// ---------------------------------------------------------------------------
__global__ __launch_bounds__(256) void prep_kernel(
    const float* __restrict__ x, uint4* __restrict__ img,
    float* __restrict__ dsq)
{
    const int blk = blockIdx.x;                 // b*NT + s
    const int b = blk / NT, s = blk % NT;
    const int t = threadIdx.x;
    const float4* src = (const float4*)x + (size_t)(b * DIM + s * TS) * 25;
    uint4* dst = img + (size_t)blk * TILE_U4;

    #pragma unroll
    for (int ff = 0; ff < 4; ++ff) {
        const int f = t + ff * 256;
        const int r = f >> 4, c = f & 15;
        uint4 p = {0u, 0u, 0u, 0u};
        if (c <= 12) {
            float4 lo = src[(size_t)r * 25 + 2 * c];
            float4 hi = make_float4(0.f, 0.f, 0.f, 0.f);
            if (c < 12) hi = src[(size_t)r * 25 + 2 * c + 1];
            p.x = pk_bf16(lo.x, lo.y);
            p.y = pk_bf16(lo.z, lo.w);
            p.z = pk_bf16(hi.x, hi.y);
            p.w = pk_bf16(hi.z, hi.w);
        }
        dst[r * KCH + (c ^ (r & 15))] = p;
    }

    // per-row sum of squares of bf16-rounded values: 4 threads per row
    const int r = t >> 2, q = t & 3;
    float sq = 0.f;
    for (int j = q; j < 25; j += 4) {
        float4 v = src[(size_t)r * 25 + j];
        float a0 = bfr(v.x), a1 = bfr(v.y), a2 = bfr(v.z), a3 = bfr(v.w);
        sq += a0 * a0 + a1 * a1 + a2 * a2 + a3 * a3;
    }
    sq += __shfl_xor(sq, 1);
    sq += __shfl_xor(sq, 2);
    if (q == 0) dsq[b * DIM + s * TS + r] = sq;
}

// ---------------------------------------------------------------------------
// K1: one block per (b, strip s, j-parity h).  Partial dcov row sums for rows
// [s*64, s*64+64) over j-tiles of parity h.  Coalesced LDS staging, register
// A-frags, one sync per j-iter, no shfl in the loop, no atomics.
// ---------------------------------------------------------------------------
__global__ __launch_bounds__(256, 3) void strip_kernel(
    const uint4* __restrict__ img, const float* __restrict__ dsq,
    const float* __restrict__ temp, float* __restrict__ rowsum_part)
{
    __shared__ uint4 xown[TILE_U4];
    __shared__ uint4 xj[2][TILE_U4];
    __shared__ float dAll[DIM];
    __shared__ float rpartw[2][TS];

    const int raw = blockIdx.x;                       // 1280 % 8 == 0
    const int bid = (raw & 7) * 160 + (raw >> 3);     // XCD-grouped
    const int b = bid / 20, rem = bid % 20;
    const int s = rem >> 1, h = rem & 1;
    const int t = threadIdx.x, wv = t >> 6, lane = t & 63;
    const int l31 = lane & 31, khalf = lane >> 5;
    const int iq = wv & 1, jq = wv >> 1;
    const float tts = expf(temp[0]);
    const char* base = (const char*)(img + (size_t)b * NT * TILE_U4);

    stage_tile16(base + (size_t)s * TILE_B, (char*)xown, wv, lane);
    stage_tile16(base + (size_t)h * TILE_B, (char*)xj[0], wv, lane);
    for (int k = t; k < DIM; k += 256) dAll[k] = dsq[b * DIM + k];
    __syncthreads();

    const int irow = iq * 32 + l31;
    bf16x8 ifr[7];
    #pragma unroll
    for (int kk = 0; kk < 7; ++kk) {
        const int c = kk * 2 + khalf;
        ifr[kk] = *(const bf16x8*)&xown[irow * KCH + (c ^ (irow & 15))];
    }
    const float dic = dAll[s * TS + irow];
    const int jr = jq * 32 + l31;

    float rsum = 0.f;
    #pragma unroll
    for (int jj = 0; jj < 5; ++jj) {
        const int jt = h + 2 * jj;
        if (jj < 4)
            stage_tile16(base + (size_t)(jt + 2) * TILE_B,
                         (char*)xj[(jj + 1) & 1], wv, lane);
        const uint4* buf = xj[jj & 1];
        bf16x8 jfr[7];
        #pragma unroll
        for (int kk = 0; kk < 7; ++kk) {
            const int c = kk * 2 + khalf;
            jfr[kk] = *(const bf16x8*)&buf[jr * KCH + (c ^ (jr & 15))];
        }
        f32x16 acc = {};
        #pragma unroll
        for (int kk = 0; kk < 7; ++kk)
            acc = __builtin_amdgcn_mfma_f32_32x32x16_bf16(jfr[kk], ifr[kk],
                                                          acc, 0, 0, 0);
        const bool dg = (jt == s);
        #pragma unroll
        for (int r = 0; r < 16; ++r) {
            const int rf = (r & 3) + 8 * (r >> 2) + 4 * khalf;
            const int jrow = jq * 32 + rf;
            const float dj = dAll[jt * TS + jrow];
            float u = dj + dic - 2.f * acc[r];
            rsum += (dg && jrow == irow)
                  ? SQEPS : fsq(tts * fmaxf(u, 0.f) + EPS);
        }
        __syncthreads();   // buffer consumed; next stage complete
    }

    rsum += __shfl_xor(rsum, 32);
    if (lane < 32) rpartw[jq][iq * 32 + lane] = rsum;
    __syncthreads();
    if (t < TS)
        rowsum_part[h * (B_ * DIM) + b * DIM + s * TS + t]
            = rpartw[0][t] + rpartw[1][t];
}

// ---------------------------------------------------------------------------
// K2: one block per (b, strip-pair p, j-parity h).  Owns triu tiles of strips
// {p, 9-p} with j-parity h (5-6 tiles).  LDS-staged frags, e[]-centering.
// ---------------------------------------------------------------------------
__global__ __launch_bounds__(256, 3) void write_kernel(
    const uint4* __restrict__ img, const float* __restrict__ dsq,
    const float* __restrict__ temp, const float* __restrict__ rowsum_part,
    float* __restrict__ out)
{
    __shared__ uint4 xi[TILE_U4];
    __shared__ uint4 xjb[2][TILE_U4];
    __shared__ float e[DIM];
    __shared__ float dAll[DIM];
    __shared__ float red4[4];

    const int raw = blockIdx.x;                       // 640 % 8 == 0
    const int bid = (raw & 7) * 80 + (raw >> 3);      // XCD-grouped
    const int b = bid / 10, rem = bid % 10;
    const int p = rem >> 1, h = rem & 1;
    const int t = threadIdx.x, wv = t >> 6, lane = t & 63;
    const int l31 = lane & 31, khalf = lane >> 5;
    const int wm = wv >> 1, wn = wv & 1;
    const float tts = expf(temp[0]);
    const char* base = (const char*)(img + (size_t)b * NT * TILE_U4);
    const float* r0 = rowsum_part + b * DIM;
    const float* r1 = rowsum_part + (B_ * DIM) + b * DIM;

    // e[k] = tm/2 - rowmean[k]  =>  centered = v + e[gi] + e[gj]
    float ps = 0.f;
    for (int k = t; k < DIM; k += 256) {
        float rs = r0[k] + r1[k];
        e[k] = rs;
        dAll[k] = dsq[b * DIM + k];
        ps += rs;
    }
    ps += __shfl_xor(ps, 1);  ps += __shfl_xor(ps, 2);
    ps += __shfl_xor(ps, 4);  ps += __shfl_xor(ps, 8);
    ps += __shfl_xor(ps, 16); ps += __shfl_xor(ps, 32);
    if (lane == 0) red4[wv] = ps;
    __syncthreads();
    const float tm = (red4[0] + red4[1] + red4[2] + red4[3])
                   * (1.0f / ((float)DIM * (float)DIM));
    const float invD = 1.0f / (float)DIM;
    for (int k = t; k < DIM; k += 256)
        e[k] = 0.5f * tm - e[k] * invD;

    // stage first strip tile + its first j tile
    {
        const int jf0 = p + ((p ^ h) & 1);
        stage_tile16(base + (size_t)p * TILE_B, (char*)xi, wv, lane);
        stage_tile16(base + (size_t)jf0 * TILE_B, (char*)xjb[0], wv, lane);
    }
    __syncthreads();

    const int arow = wm * 32 + l31;
    const int brow = wn * 32 + l31;

    #pragma unroll
    for (int si = 0; si < 2; ++si) {
        const int s = si ? (9 - p) : p;
        const int jf = s + ((s ^ h) & 1);
        if (jf >= NT) continue;
        if (si == 1) {   // restage strip tile + first j tile
            stage_tile16(base + (size_t)s * TILE_B, (char*)xi, wv, lane);
            stage_tile16(base + (size_t)jf * TILE_B, (char*)xjb[0], wv, lane);
            __syncthreads();
        }
        const int i0 = s * TS;
        bf16x8 afr[7];
        #pragma unroll
        for (int kk = 0; kk < 7; ++kk) {
            const int c = kk * 2 + khalf;
            afr[kk] = *(const bf16x8*)&xi[arow * KCH + (c ^ (arow & 15))];
        }

        for (int j = jf, idx = 0; j < NT; j += 2, ++idx) {
            if (j + 2 < NT)
                stage_tile16(base + (size_t)(j + 2) * TILE_B,
                             (char*)xjb[(idx + 1) & 1], wv, lane);
            const uint4* buf = xjb[idx & 1];
            bf16x8 bfr7[7];
            #pragma unroll
            for (int kk = 0; kk < 7; ++kk) {
                const int c = kk * 2 + khalf;
                bfr7[kk] = *(const bf16x8*)&buf[brow * KCH + (c ^ (brow & 15))];
            }
            f32x16 acc = {};
            #pragma unroll
            for (int kk = 0; kk < 7; ++kk)
                acc = __builtin_amdgcn_mfma_f32_32x32x16_bf16(afr[kk], bfr7[kk],
                                                              acc, 0, 0, 0);
            const int j0 = j * TS;
            const int gj = j0 + brow;
            const float djc = dAll[gj], ejc = e[gj];
            const bool dg = (j == s);
            #pragma unroll
            for (int g = 0; g < 4; ++g) {
                const int rbase = wm * 32 + 8 * g + 4 * khalf;
                const float4 e4 = *(const float4*)&e[i0 + rbase];
                const float4 d4 = *(const float4*)&dAll[i0 + rbase];
                #pragma unroll
                for (int q = 0; q < 4; ++q) {
                    const int r  = 4 * g + q;
                    const int gi = i0 + rbase + q;
                    float u = ((const float*)&d4)[q] + djc - 2.f * acc[r];
                    float v = (dg && gi == gj)
                            ? SQEPS : fsq(tts * fmaxf(u, 0.f) + EPS);
                    float cv = v + ((const float*)&e4)[q] + ejc;
                    unsigned idx32 = (unsigned)b * TRI + (unsigned)gi * DIM
                                   - (((unsigned)gi * (unsigned)(gi - 1)) >> 1)
                                   - (unsigned)gi + (unsigned)gj;
                    if (!dg || gj >= gi) out[idx32] = cv;
                }
            }
            __syncthreads();   // buffer consumed; next stage complete
        }
    }
}

extern "C" void kernel_launch(void* const* d_in, const int* in_sizes, int n_in,
                              void* d_out, int out_size, void* d_ws, size_t ws_size,
                              hipStream_t stream)
{
    const float* x    = (const float*)d_in[0];
    const float* temp = (const float*)d_in[1];
    float* out         = (float*)d_out;

    float* rowsum_part = (float*)d_ws;                    // [2][B_*DIM]
    float* dsq         = rowsum_part + 2 * B_ * DIM;      // [B_*DIM]
    uint4* img         = (uint4*)(dsq + B_ * DIM);        // 10.5 MB

    prep_kernel <<<B_ * NT,     256, 0, stream>>>(x, img, dsq);
    strip_kernel<<<2 * B_ * NT, 256, 0, stream>>>(img, dsq, temp, rowsum_part);
    write_kernel<<<B_ * NT,     256, 0, stream>>>(img, dsq, temp, rowsum_part, out);
}

// Round 10
// 47.686 us; speedup vs baseline: 1.8269x; 1.0760x over previous
//
#include <hip/hip_runtime.h>
#include <hip/hip_bf16.h>

#define B_    64
#define DIM   640
#define TS    64
#define NT    10        // DIM/TS
#define TRI   205120    // DIM*(DIM+1)/2
#define EPS   1e-5f
#define SQEPS 3.1622776601683794e-3f
#define KCH   16        // uint4 chunks per img row (256 B row stride)
#define TILE_U4 1024    // uint4 per 64-row tile image (16 KB)
#define TILE_B  16384

typedef __attribute__((ext_vector_type(8)))  short bf16x8;
typedef __attribute__((ext_vector_type(16))) float f32x16;

__device__ inline unsigned pk_bf16(float a, float b) {
    __hip_bfloat162 h = __float22bfloat162_rn(float2{a, b});
    return *reinterpret_cast<unsigned*>(&h);
}
__device__ inline float bfr(float x) {
    return __bfloat162float(__float2bfloat16(x));
}
__device__ inline float fsq(float x) { return __builtin_amdgcn_sqrtf(x); }

__device__ inline void gload_lds16(const void* g, void* l) {
    __builtin_amdgcn_global_load_lds(
        (const __attribute__((address_space(1))) unsigned*)g,
        (__attribute__((address_space(3))) unsigned*)l, 16, 0, 0);
}
// stage one 16 KB tile: 4 waves x 4 segs x 64 lanes x 16 B (coalesced)
__device__ inline void stage_tile16(const char* __restrict__ gt, char* lt,
                                    int wv, int lane) {
    #pragma unroll
    for (int it = 0; it < 4; ++it) {
        const int seg = (wv * 4 + it) * 1024;
        gload_lds16(gt + seg + lane * 16, lt + seg);
    }
}

// ---------------------------------------------------------------------------
// K0 prep: per (b,s) convert 64x100 fp32 strip -> swizzled bf16 img tile
// (K zero-padded) + per-row sum of squares of bf16-rounded values.
// ---------------------------------------------------------------------------
__global__ __launch_bounds__(256) void prep_kernel(
    const float* __restrict__ x, uint4* __restrict__ img,
    float* __restrict__ dsq)
{
    const int blk = blockIdx.x;                 // b*NT + s
    const int b = blk / NT, s = blk % NT;
    const int t = threadIdx.x;
    const float4* src = (const float4*)x + (size_t)(b * DIM + s * TS) * 25;
    uint4* dst = img + (size_t)blk * TILE_U4;

    #pragma unroll
    for (int ff = 0; ff < 4; ++ff) {
        const int f = t + ff * 256;
        const int r = f >> 4, c = f & 15;
        uint4 p = {0u, 0u, 0u, 0u};
        if (c <= 12) {
            float4 lo = src[(size_t)r * 25 + 2 * c];
            float4 hi = make_float4(0.f, 0.f, 0.f, 0.f);
            if (c < 12) hi = src[(size_t)r * 25 + 2 * c + 1];
            p.x = pk_bf16(lo.x, lo.y);
            p.y = pk_bf16(lo.z, lo.w);
            p.z = pk_bf16(hi.x, hi.y);
            p.w = pk_bf16(hi.z, hi.w);
        }
        dst[r * KCH + (c ^ (r & 15))] = p;
    }

    // per-row sum of squares of bf16-rounded values: 4 threads per row
    const int r = t >> 2, q = t & 3;
    float sq = 0.f;
    for (int j = q; j < 25; j += 4) {
        float4 v = src[(size_t)r * 25 + j];
        float a0 = bfr(v.x), a1 = bfr(v.y), a2 = bfr(v.z), a3 = bfr(v.w);
        sq += a0 * a0 + a1 * a1 + a2 * a2 + a3 * a3;
    }
    sq += __shfl_xor(sq, 1);
    sq += __shfl_xor(sq, 2);
    if (q == 0) dsq[b * DIM + s * TS + r] = sq;
}

// ---------------------------------------------------------------------------
// K1: one block per (b, strip s, j-parity h).  Partial dcov row sums for rows
// [s*64, s*64+64) over j-tiles of parity h.  A-frags direct from L2 (no LDS
// staging); j-tiles double-buffered via global_load_lds.
// ---------------------------------------------------------------------------
__global__ __launch_bounds__(256, 4) void strip_kernel(
    const uint4* __restrict__ img, const float* __restrict__ dsq,
    const float* __restrict__ temp, float* __restrict__ rowsum_part)
{
    __shared__ uint4 xj[2][TILE_U4];      // 32 KB
    __shared__ float dAll[DIM];
    __shared__ float rpartw[2][TS];

    const int raw = blockIdx.x;                       // 1280 % 8 == 0
    const int bid = (raw & 7) * 160 + (raw >> 3);     // XCD-grouped
    const int b = bid / 20, rem = bid % 20;
    const int s = rem >> 1, h = rem & 1;
    const int t = threadIdx.x, wv = t >> 6, lane = t & 63;
    const int l31 = lane & 31, khalf = lane >> 5;
    const int iq = wv & 1, jq = wv >> 1;
    const float tts = expf(temp[0]);
    const char* base = (const char*)(img + (size_t)b * NT * TILE_U4);

    stage_tile16(base + (size_t)h * TILE_B, (char*)xj[0], wv, lane);
    for (int k = t; k < DIM; k += 256) dAll[k] = dsq[b * DIM + k];

    // own-strip A-fragments straight from global (L2-hot, one-time)
    const int irow = iq * 32 + l31;
    const uint4* own = img + (size_t)(b * NT + s) * TILE_U4;
    bf16x8 ifr[7];
    #pragma unroll
    for (int kk = 0; kk < 7; ++kk) {
        const int c = kk * 2 + khalf;
        ifr[kk] = *(const bf16x8*)&own[irow * KCH + (c ^ (irow & 15))];
    }
    const float dic = dsq[b * DIM + s * TS + irow];
    const int jr = jq * 32 + l31;
    __syncthreads();

    float rsum = 0.f;
    #pragma unroll
    for (int jj = 0; jj < 5; ++jj) {
        const int jt = h + 2 * jj;
        if (jj < 4)
            stage_tile16(base + (size_t)(jt + 2) * TILE_B,
                         (char*)xj[(jj + 1) & 1], wv, lane);
        const uint4* buf = xj[jj & 1];
        bf16x8 jfr[7];
        #pragma unroll
        for (int kk = 0; kk < 7; ++kk) {
            const int c = kk * 2 + khalf;
            jfr[kk] = *(const bf16x8*)&buf[jr * KCH + (c ^ (jr & 15))];
        }
        f32x16 acc = {};
        #pragma unroll
        for (int kk = 0; kk < 7; ++kk)
            acc = __builtin_amdgcn_mfma_f32_32x32x16_bf16(jfr[kk], ifr[kk],
                                                          acc, 0, 0, 0);
        const bool dg = (jt == s);
        #pragma unroll
        for (int r = 0; r < 16; ++r) {
            const int rf = (r & 3) + 8 * (r >> 2) + 4 * khalf;
            const int jrow = jq * 32 + rf;
            const float dj = dAll[jt * TS + jrow];
            float u = dj + dic - 2.f * acc[r];
            rsum += (dg && jrow == irow)
                  ? SQEPS : fsq(tts * fmaxf(u, 0.f) + EPS);
        }
        __syncthreads();   // buffer consumed; next stage complete
    }

    rsum += __shfl_xor(rsum, 32);
    if (lane < 32) rpartw[jq][iq * 32 + lane] = rsum;
    __syncthreads();
    if (t < TS)
        rowsum_part[h * (B_ * DIM) + b * DIM + s * TS + t]
            = rpartw[0][t] + rpartw[1][t];
}

// ---------------------------------------------------------------------------
// K2: one block per (b, strip-pair p, j-parity h).  Owns triu tiles of strips
// {p, 9-p} with j-parity h.  A-frags direct from L2; e[]-centering; uniform
// branch-free symmetric stores.
// ---------------------------------------------------------------------------
__global__ __launch_bounds__(256, 4) void write_kernel(
    const uint4* __restrict__ img, const float* __restrict__ dsq,
    const float* __restrict__ temp, const float* __restrict__ rowsum_part,
    float* __restrict__ out)
{
    __shared__ uint4 xjb[2][TILE_U4];     // 32 KB
    __shared__ float e[DIM];
    __shared__ float dAll[DIM];
    __shared__ float red4[4];

    const int raw = blockIdx.x;                       // 640 % 8 == 0
    const int bid = (raw & 7) * 80 + (raw >> 3);      // XCD-grouped
    const int b = bid / 10, rem = bid % 10;
    const int p = rem >> 1, h = rem & 1;
    const int t = threadIdx.x, wv = t >> 6, lane = t & 63;
    const int l31 = lane & 31, khalf = lane >> 5;
    const int wm = wv >> 1, wn = wv & 1;
    const float tts = expf(temp[0]);
    const char* base = (const char*)(img + (size_t)b * NT * TILE_U4);
    const float* r0 = rowsum_part + b * DIM;
    const float* r1 = rowsum_part + (B_ * DIM) + b * DIM;

    // stage first j-tile of strip p early (overlaps e[] build)
    const int jf0 = p + ((p ^ h) & 1);
    stage_tile16(base + (size_t)jf0 * TILE_B, (char*)xjb[0], wv, lane);

    // e[k] = tm/2 - rowmean[k]  =>  centered = v + e[gi] + e[gj]
    float ps = 0.f;
    for (int k = t; k < DIM; k += 256) {
        float rs = r0[k] + r1[k];
        e[k] = rs;
        dAll[k] = dsq[b * DIM + k];
        ps += rs;
    }
    ps += __shfl_xor(ps, 1);  ps += __shfl_xor(ps, 2);
    ps += __shfl_xor(ps, 4);  ps += __shfl_xor(ps, 8);
    ps += __shfl_xor(ps, 16); ps += __shfl_xor(ps, 32);
    if (lane == 0) red4[wv] = ps;
    __syncthreads();
    const float tm = (red4[0] + red4[1] + red4[2] + red4[3])
                   * (1.0f / ((float)DIM * (float)DIM));
    const float invD = 1.0f / (float)DIM;
    for (int k = t; k < DIM; k += 256)
        e[k] = 0.5f * tm - e[k] * invD;
    __syncthreads();

    const int arow = wm * 32 + l31;
    const int brow = wn * 32 + l31;

    #pragma unroll
    for (int si = 0; si < 2; ++si) {
        const int s = si ? (9 - p) : p;
        const int jf = s + ((s ^ h) & 1);
        if (jf >= NT) continue;
        if (si == 1) {   // stage first j tile of second strip
            stage_tile16(base + (size_t)jf * TILE_B, (char*)xjb[0], wv, lane);
            __syncthreads();
        }
        const int i0 = s * TS;
        // A-fragments straight from global (L2-hot, once per strip)
        const uint4* ownt = img + (size_t)(b * NT + s) * TILE_U4;
        bf16x8 afr[7];
        #pragma unroll
        for (int kk = 0; kk < 7; ++kk) {
            const int c = kk * 2 + khalf;
            afr[kk] = *(const bf16x8*)&ownt[arow * KCH + (c ^ (arow & 15))];
        }

        for (int j = jf, idx = 0; j < NT; j += 2, ++idx) {
            if (j + 2 < NT)
                stage_tile16(base + (size_t)(j + 2) * TILE_B,
                             (char*)xjb[(idx + 1) & 1], wv, lane);
            const uint4* buf = xjb[idx & 1];
            bf16x8 bfr7[7];
            #pragma unroll
            for (int kk = 0; kk < 7; ++kk) {
                const int c = kk * 2 + khalf;
                bfr7[kk] = *(const bf16x8*)&buf[brow * KCH + (c ^ (brow & 15))];
            }
            f32x16 acc = {};
            #pragma unroll
            for (int kk = 0; kk < 7; ++kk)
                acc = __builtin_amdgcn_mfma_f32_32x32x16_bf16(afr[kk], bfr7[kk],
                                                              acc, 0, 0, 0);
            const int j0 = j * TS;
            const int gj = j0 + brow;
            const float djc = dAll[gj], ejc = e[gj];
            #pragma unroll
            for (int g = 0; g < 4; ++g) {
                const int rbase = wm * 32 + 8 * g + 4 * khalf;
                const float4 e4 = *(const float4*)&e[i0 + rbase];
                const float4 d4 = *(const float4*)&dAll[i0 + rbase];
                #pragma unroll
                for (int q = 0; q < 4; ++q) {
                    const int r  = 4 * g + q;
                    const int gi = i0 + rbase + q;
                    float u = ((const float*)&d4)[q] + djc - 2.f * acc[r];
                    float v = (gi == gj) ? SQEPS
                                         : fsq(tts * fmaxf(u, 0.f) + EPS);
                    float cv = v + ((const float*)&e4)[q] + ejc;
                    // branch-free symmetric store (diag tiles: mirrored lanes
                    // write the same value to the same address -- benign)
                    const unsigned lo = (unsigned)min(gi, gj);
                    const unsigned hi2 = (unsigned)max(gi, gj);
                    unsigned idx32 = (unsigned)b * TRI + lo * DIM
                                   - ((lo * (lo - 1)) >> 1) - lo + hi2;
                    out[idx32] = cv;
                }
            }
            __syncthreads();   // buffer consumed; next stage complete
        }
    }
}

extern "C" void kernel_launch(void* const* d_in, const int* in_sizes, int n_in,
                              void* d_out, int out_size, void* d_ws, size_t ws_size,
                              hipStream_t stream)
{
    const float* x    = (const float*)d_in[0];
    const float* temp = (const float*)d_in[1];
    float* out         = (float*)d_out;

    float* rowsum_part = (float*)d_ws;                    // [2][B_*DIM]
    float* dsq         = rowsum_part + 2 * B_ * DIM;      // [B_*DIM]
    uint4* img         = (uint4*)(dsq + B_ * DIM);        // 10.5 MB

    prep_kernel <<<B_ * NT,     256, 0, stream>>>(x, img, dsq);
    strip_kernel<<<2 * B_ * NT, 256, 0, stream>>>(img, dsq, temp, rowsum_part);
    write_kernel<<<B_ * NT,     256, 0, stream>>>(img, dsq, temp, rowsum_part, out);
}